// Round 5
// baseline (418.618 us; speedup 1.0000x reference)
//
#include <hip/hip_runtime.h>
#include <math.h>

#define N_FFT 4096
#define HOP   1024
#define PAD   2048
#define NBINS 2049
#define NFRM  257
#define BATCH 8
#define TLEN  262144          // 2^18
#define M     2048            // complex FFT size (real-packed)
#define TWO_PI 6.2831853071795864769f

#define NGRP  257             // groups of 8 bins (2056 padded bins)
#define CKG   5               // groups per split
#define S_SPLIT 52            // ceil(257/5)
#define USLAB (8 * 75 * NFRM) // floats per split-slab = 154200

__device__ __forceinline__ int reflect_idx(int s) {
    if (s < 0) s = -s;
    if (s >= TLEN) s = 2 * (TLEN - 1) - s;
    return s;
}

__device__ __forceinline__ unsigned short f2bf(float f) {
    unsigned int u = __float_as_uint(f);
    unsigned int r = (u + 0x7FFFu + ((u >> 16) & 1u)) >> 16;   // RTNE
    return (unsigned short)r;
}

// ---------------- Kernel T: trig tables ----------------
__global__ __launch_bounds__(256) void tables_kernel(float2* __restrict__ twid_g,
                                                     float* __restrict__ wtab,
                                                     float2* __restrict__ utw) {
    int i = blockIdx.x * 256 + threadIdx.x;
    if (i < M / 2) {
        float sv, cv;
        sincosf(-(TWO_PI * (float)i) / (float)M, &sv, &cv);
        twid_g[i] = make_float2(cv, sv);
    }
    if (i < N_FFT) {
        wtab[i] = 0.5f - 0.5f * cosf((TWO_PI / (float)N_FFT) * (float)i);
    }
    if (i < NBINS) {
        float sv, cv;
        sincosf(-(TWO_PI * (float)i) / (float)N_FFT, &sv, &cv);
        utw[i] = make_float2(cv, sv);
    }
}

// ---------------- Kernel P: pad w1 -> w1p[2056*300] ----------------
__global__ __launch_bounds__(256) void w1pad_kernel(const float* __restrict__ w1,
                                                    float* __restrict__ w1p) {
    int i = blockIdx.x * 256 + threadIdx.x;
    if (i >= 2056 * 300) return;
    int bin = i / 300;
    w1p[i] = (bin < NBINS) ? w1[i] : 0.f;
}

// ---------------- Kernel 1: windowed frame -> rfft -> bf16 grouped spec ------------
// specg: uint per bin, layout [(cb*NGRP + grp)*NFRM + f]*8 + q  (bin = grp*8+q)
__global__ __launch_bounds__(256) void stft_kernel(const float* __restrict__ x,
                                                   const float2* __restrict__ twid_g,
                                                   const float* __restrict__ wtab,
                                                   const float2* __restrict__ utw,
                                                   uint4* __restrict__ specg) {
    __shared__ float2 zbuf[M];
    __shared__ float2 twid[M / 2];

    int wg = blockIdx.x;
    int f  = wg % NFRM;
    int ch = (wg / NFRM) & 1;
    int b  = wg / (NFRM * 2);
    int cb = b * 2 + ch;
    const float* xc = x + (size_t)cb * TLEN;
    int tid = threadIdx.x;

    for (int t = tid; t < M / 2; t += 256) twid[t] = twid_g[t];

    int base = f * HOP - PAD;
    const float2* wt2 = (const float2*)wtab;
    for (int idx = tid; idx < M; idx += 256) {
        float2 wv = wt2[idx];
        int n0 = 2 * idx;
        float v0 = xc[reflect_idx(base + n0)] * wv.x;
        float v1 = xc[reflect_idx(base + n0 + 1)] * wv.y;
        int r = __brev((unsigned)idx) >> 21;  // 11-bit reverse
        zbuf[r] = make_float2(v0, v1);
    }
    __syncthreads();

    for (int s = 0; s < 11; s++) {
        int half = 1 << s;
        for (int t = tid; t < M / 2; t += 256) {
            int blk = t >> s;
            int pos = t & (half - 1);
            int i0 = (blk << (s + 1)) + pos;
            int i1 = i0 + half;
            float2 wv = twid[pos << (10 - s)];
            float2 u = zbuf[i0];
            float2 v = zbuf[i1];
            float tr = v.x * wv.x - v.y * wv.y;
            float ti = v.x * wv.y + v.y * wv.x;
            zbuf[i0] = make_float2(u.x + tr, u.y + ti);
            zbuf[i1] = make_float2(u.x - tr, u.y - ti);
        }
        __syncthreads();
    }

    // epilogue: thread t -> group t (8 consecutive bins), tid 0 also does group 256
    for (int grp = tid; grp < NGRP; grp += 256) {
        unsigned int vals[8];
#pragma unroll
        for (int q = 0; q < 8; q++) {
            int k = grp * 8 + q;
            unsigned int pv = 0u;
            if (k <= 2048) {
                int ka = k & (M - 1);
                int kb = (M - k) & (M - 1);
                float2 Zk = zbuf[ka];
                float2 Zc = zbuf[kb];
                Zc.y = -Zc.y;
                float ex = 0.5f * (Zk.x + Zc.x);
                float ey = 0.5f * (Zk.y + Zc.y);
                float dx = Zk.x - Zc.x;
                float dy = Zk.y - Zc.y;
                float ox = 0.5f * dy;
                float oy = -0.5f * dx;
                float2 tw = utw[k];
                float xr = ex + tw.x * ox - tw.y * oy;
                float xi = ey + tw.x * oy + tw.y * ox;
                pv = ((unsigned int)f2bf(xi) << 16) | (unsigned int)f2bf(xr);
            }
            vals[q] = pv;
        }
        size_t bidx = (((size_t)cb * NGRP + grp) * NFRM + f) * 2;
        specg[bidx]     = make_uint4(vals[0], vals[1], vals[2], vals[3]);
        specg[bidx + 1] = make_uint4(vals[4], vals[5], vals[6], vals[7]);
    }
}

// ---------------- Kernel 2: U-form layer-1 partials (frame-per-lane, coalesced) ----
__global__ __launch_bounds__(320) void mlp_u_kernel(const uint4* __restrict__ specg,
                                                    const float* __restrict__ w1p,
                                                    float* __restrict__ partial) {
    int blk = blockIdx.x;          // 8 * S_SPLIT
    int b = blk & 7;
    int s = blk >> 3;
    int fr = threadIdx.x;          // frame lane
    int frc = fr < NFRM ? fr : NFRM - 1;

    int g0 = s * CKG;
    int g1 = g0 + CKG; if (g1 > NGRP) g1 = NGRP;

    float acc[5][15];
#pragma unroll
    for (int g = 0; g < 5; g++)
#pragma unroll
        for (int j = 0; j < 15; j++) acc[g][j] = 0.f;

    for (int grp = g0; grp < g1; ++grp) {
        size_t Lb = (((size_t)(b * 2 + 0) * NGRP + grp) * NFRM + frc) * 2;
        size_t Rb = (((size_t)(b * 2 + 1) * NGRP + grp) * NFRM + frc) * 2;
        uint4 l0 = specg[Lb], l1 = specg[Lb + 1];
        uint4 r0 = specg[Rb], r1 = specg[Rb + 1];
        unsigned int lvals[8] = {l0.x, l0.y, l0.z, l0.w, l1.x, l1.y, l1.z, l1.w};
        unsigned int rvals[8] = {r0.x, r0.y, r0.z, r0.w, r1.x, r1.y, r1.z, r1.w};
        const float* wq = w1p + (size_t)grp * 8 * 300;
#pragma unroll
        for (int q = 0; q < 8; q++) {
            unsigned int lv = lvals[q];
            unsigned int rv = rvals[q];
            float Lr = __uint_as_float(lv << 16);
            float Li = __uint_as_float(lv & 0xFFFF0000u);
            float Rr = __uint_as_float(rv << 16);
            float Ri = __uint_as_float(rv & 0xFFFF0000u);
            const float* wb = wq + q * 300;
#pragma unroll
            for (int g = 0; g < 5; g++) {
#pragma unroll
                for (int c = 0; c < 4; c++) {
                    float fv = (c == 0) ? Lr : (c == 1) ? Rr : (c == 2) ? Li : Ri;
                    const float* wr = wb + (g * 4 + c) * 15;
#pragma unroll
                    for (int j = 0; j < 15; j++) acc[g][j] += fv * wr[j];
                }
            }
        }
    }

    if (fr < NFRM) {
        float* pbase = partial + (size_t)(s * 8 + b) * 75 * NFRM + fr;
#pragma unroll
        for (int g = 0; g < 5; g++)
#pragma unroll
            for (int j = 0; j < 15; j++)
                pbase[(size_t)(g * 15 + j) * NFRM] = acc[g][j];
    }
}

// ---------------- Kernel 2b: sum split partials -> U ----------------
__global__ __launch_bounds__(256) void combine1_kernel(const float* __restrict__ partial,
                                                       float* __restrict__ U) {
    int i = blockIdx.x * 256 + threadIdx.x;
    if (i >= USLAB) return;
    float v = 0.f;
    for (int s = 0; s < S_SPLIT; s++) v += partial[(size_t)s * USLAB + i];
    U[i] = v;
}

// ---------------- Kernel 2c: context-fold + MLP 2/3 -> mask ----------------
__global__ __launch_bounds__(256) void mask_kernel(const float* __restrict__ U,
                                                   const float* __restrict__ b1,
                                                   const float* __restrict__ w2,
                                                   const float* __restrict__ b2,
                                                   const float* __restrict__ w3,
                                                   const float* __restrict__ b3,
                                                   float* __restrict__ mask) {
    int i = blockIdx.x * 256 + threadIdx.x;
    if (i >= BATCH * NFRM) return;
    int b = i / NFRM;
    int f = i - b * NFRM;

    float h1[15];
#pragma unroll
    for (int j = 0; j < 15; j++) h1[j] = b1[j];
#pragma unroll
    for (int g = 0; g < 5; g++) {
        int fr = f - 2 + g;
        if (fr >= 0 && fr < NFRM) {
#pragma unroll
            for (int j = 0; j < 15; j++)
                h1[j] += U[(size_t)(b * 75 + g * 15 + j) * NFRM + fr];
        }
    }
#pragma unroll
    for (int j = 0; j < 15; j++) h1[j] = h1[j] > 0.f ? h1[j] : 0.f;

    float h2[10];
#pragma unroll
    for (int k = 0; k < 10; k++) {
        float sv = b2[k];
#pragma unroll
        for (int j = 0; j < 15; j++) sv += h1[j] * w2[j * 10 + k];
        h2[k] = sv > 0.f ? sv : 0.f;
    }
    float v = b3[0];
#pragma unroll
    for (int k = 0; k < 10; k++) v += h2[k] * w3[k];
    mask[i] = 1.f / (1.f + expf(-v));
}

// ---------------- Kernel 3: analytic masked ISTFT (overlap-add ratio) ----------------
__global__ __launch_bounds__(256) void ola_kernel(const float* __restrict__ x,
                                                  const float* __restrict__ mask,
                                                  const float* __restrict__ wtab,
                                                  float* __restrict__ out) {
    int idx = blockIdx.x * 256 + threadIdx.x;
    int t  = idx & (TLEN - 1);
    int bc = idx >> 18;
    int b  = bc >> 1;
    int tau = t + PAD;
    int hi = tau >> 10; if (hi > NFRM - 1) hi = NFRM - 1;
    int lo = (tau - 3072) >> 10; if (lo < 0) lo = 0;
    float s0 = 0.f, s1 = 0.f;
    const float* mb = mask + b * NFRM;
    for (int f = lo; f <= hi; f++) {
        int n = tau - (f << 10);
        float w = wtab[n];
        float w2v = w * w;
        s0 += w2v;
        s1 += mb[f] * w2v;
    }
    float denom = (s0 > 1e-11f) ? s0 : 1.0f;
    out[idx] = x[idx] * (s1 / denom);
}

// ---------------- launch ----------------
extern "C" void kernel_launch(void* const* d_in, const int* in_sizes, int n_in,
                              void* d_out, int out_size, void* d_ws, size_t ws_size,
                              hipStream_t stream) {
    const float* x  = (const float*)d_in[0];
    const float* w1 = (const float*)d_in[1];
    const float* b1 = (const float*)d_in[2];
    const float* w2 = (const float*)d_in[3];
    const float* b2 = (const float*)d_in[4];
    const float* w3 = (const float*)d_in[5];
    const float* b3 = (const float*)d_in[6];

    char* wsp = (char*)d_ws;
    size_t off = 0;
    auto alloc = [&](size_t bytes) { void* p = wsp + off; off = (off + bytes + 511) & ~(size_t)511; return p; };

    uint4* specg   = (uint4*)alloc((size_t)BATCH * 2 * NGRP * NFRM * 32);   // 33.8 MB
    float* partial = (float*)alloc((size_t)S_SPLIT * USLAB * 4);            // 32.1 MB
    float* U       = (float*)alloc((size_t)USLAB * 4);                      // 0.62 MB
    float* w1p     = (float*)alloc((size_t)2056 * 300 * 4);                 // 2.47 MB
    float* mask    = (float*)alloc((size_t)BATCH * NFRM * 4);
    float2* twid_g = (float2*)alloc((size_t)(M / 2) * 8);
    float* wtab    = (float*)alloc((size_t)N_FFT * 4);
    float2* utw    = (float2*)alloc((size_t)NBINS * 8);
    float* out = (float*)d_out;

    tables_kernel<<<16, 256, 0, stream>>>(twid_g, wtab, utw);
    w1pad_kernel<<<(2056 * 300 + 255) / 256, 256, 0, stream>>>(w1, w1p);
    stft_kernel<<<BATCH * 2 * NFRM, 256, 0, stream>>>(x, twid_g, wtab, utw, specg);
    mlp_u_kernel<<<8 * S_SPLIT, 320, 0, stream>>>(specg, w1p, partial);
    combine1_kernel<<<(USLAB + 255) / 256, 256, 0, stream>>>(partial, U);
    mask_kernel<<<(BATCH * NFRM + 255) / 256, 256, 0, stream>>>(U, b1, w2, b2, w3, b3, mask);
    ola_kernel<<<(BATCH * 2 * TLEN) / 256, 256, 0, stream>>>(x, mask, wtab, out);
}

// Round 8
// 136.851 us; speedup vs baseline: 3.0589x; 3.0589x over previous
//
#include <hip/hip_runtime.h>
#include <math.h>

#define N_FFT 4096
#define HOP   1024
#define PAD   2048
#define NBINS 2049
#define NFRM  257
#define BATCH 8
#define TLEN  262144          // 2^18
#define TWO_PI 6.2831853071795864769f

#define FPADR 288             // padded frames: 9 m-tiles of 32
#define BINPAD 2080           // padded bins (k-chunks of 128 => 65 chunks)
#define KW    (BINPAD * 4)    // 8320 k's (bin*4 + comp)
#define NKS   260             // k-steps of 32
#define KSPL  13              // K splits (each 5 chunks of 128 k)
#define CHPS  5               // chunks (of 128 k) per K-split
#define NCOL  80              // 5 ctx groups x 16 (j padded 15->16)

typedef short bf16x8 __attribute__((ext_vector_type(8)));
typedef float f32x4  __attribute__((ext_vector_type(4)));

__device__ __forceinline__ int reflect_idx(int s) {
    if (s < 0) s = -s;
    if (s >= TLEN) s = 2 * (TLEN - 1) - s;
    return s;
}

__device__ __forceinline__ unsigned short f2bf(float f) {
    unsigned int u = __float_as_uint(f);
    unsigned int r = (u + 0x7FFFu + ((u >> 16) & 1u)) >> 16;   // RTNE
    return (unsigned short)r;
}
__device__ __forceinline__ float bf2f(unsigned short h) {
    return __uint_as_float((unsigned int)h << 16);
}

// ---------------- Kernel T: trig/window tables ----------------
__global__ __launch_bounds__(256) void tables_kernel(float2* __restrict__ twg,
                                                     float* __restrict__ wtab) {
    int i = blockIdx.x * 256 + threadIdx.x;
    if (i < 2048) {
        float sv, cv;
        sincosf(-(TWO_PI * (float)i) / 4096.0f, &sv, &cv);
        twg[i] = make_float2(cv, sv);
    }
    if (i < N_FFT) {
        wtab[i] = 0.5f - 0.5f * cosf((TWO_PI / (float)N_FFT) * (float)i);
    }
}

// ---------------- Kernel W: pack w1 -> fragment-ready hi/lo bf16 ----------------
// Record (ks, hl, g): 1KB = 64 lanes x 16B. Lane l: n-col = g*16+(l&15) (j),
// elems e=0..7 at k = ks*32 + (l>>4)*8 + e. k = bin*4+c', c' order {Lr,Li,Rr,Ri}.
__global__ __launch_bounds__(256) void wprep_kernel(const float* __restrict__ w1,
                                                    unsigned int* __restrict__ Bwf) {
    int t = blockIdx.x * 256 + threadIdx.x;
    if (t >= NKS * 2 * 5 * 64) return;
    int l   = t & 63;
    int rec = t >> 6;
    int ks  = rec / 10;
    int r10 = rec - ks * 10;
    int hl  = r10 / 5;
    int g   = r10 - hl * 5;
    int q = l >> 4;
    int j = l & 15;

    unsigned short es[8];
#pragma unroll
    for (int e = 0; e < 8; e++) {
        int k   = ks * 32 + q * 8 + e;
        int bin = k >> 2;
        int cp  = k & 3;
        int refc = ((cp & 1) << 1) | (cp >> 1);   // {0,1,2,3}->{0,2,1,3}
        float w = 0.f;
        if (bin < NBINS && j < 15)
            w = w1[(size_t)(bin * 20 + g * 4 + refc) * 15 + j];
        unsigned short hi = f2bf(w);
        if (hl == 0) es[e] = hi;
        else         es[e] = f2bf(w - bf2f(hi));
    }
    uint4 o;
    o.x = (unsigned)es[0] | ((unsigned)es[1] << 16);
    o.y = (unsigned)es[2] | ((unsigned)es[3] << 16);
    o.z = (unsigned)es[4] | ((unsigned)es[5] << 16);
    o.w = (unsigned)es[6] | ((unsigned)es[7] << 16);
    *(uint4*)((char*)Bwf + (size_t)rec * 1024 + l * 16) = o;
}

// ---------------- Kernel 1: both channels in ONE 4096-pt complex FFT ----------------
// z = L + iR windowed; unpack L^ = 0.5(Z[k]+conj(Z[-k])), R^ = -0.5i(Z[k]-conj(Z[-k])).
// Writes Amat[b][f][k] bf16, k = bin*4 + {Lr,Li,Rr,Ri}; rows coalesced.
__global__ __launch_bounds__(256) void stft_kernel(const float* __restrict__ x,
                                                   const float2* __restrict__ twg,
                                                   const float* __restrict__ wtab,
                                                   unsigned short* __restrict__ Amat) {
    __shared__ float2 zb[4096];     // 32 KB
    int wg = blockIdx.x;
    int f  = wg % NFRM;
    int b  = wg / NFRM;
    const float* xb = x + (size_t)b * 2 * TLEN;
    int tid = threadIdx.x;
    int base = f * HOP - PAD;

    for (int n = tid; n < 4096; n += 256) {
        int ri = reflect_idx(base + n);
        float wv = wtab[n];
        float lv = xb[ri] * wv;
        float rv = xb[TLEN + ri] * wv;
        zb[__brev((unsigned)n) >> 20] = make_float2(lv, rv);   // 12-bit reverse
    }
    __syncthreads();

    for (int s = 0; s < 12; s++) {
        int half = 1 << s;
        for (int t = tid; t < 2048; t += 256) {
            int blk = t >> s;
            int pos = t & (half - 1);
            int i0 = (blk << (s + 1)) + pos;
            int i1 = i0 + half;
            float2 w = twg[pos << (11 - s)];
            float2 u = zb[i0];
            float2 v = zb[i1];
            float tr = v.x * w.x - v.y * w.y;
            float ti = v.x * w.y + v.y * w.x;
            zb[i0] = make_float2(u.x + tr, u.y + ti);
            zb[i1] = make_float2(u.x - tr, u.y - ti);
        }
        __syncthreads();
    }

    uint2* ro = (uint2*)(Amat + ((size_t)b * FPADR + f) * KW);
    for (int bin = tid; bin < BINPAD; bin += 256) {
        uint2 o = make_uint2(0u, 0u);
        if (bin <= 2048) {
            float2 Zk = zb[bin];
            float2 Z2 = zb[(4096 - bin) & 4095];
            float Lr = 0.5f * (Zk.x + Z2.x);
            float Li = 0.5f * (Zk.y - Z2.y);
            float Rr = 0.5f * (Zk.y + Z2.y);
            float Ri = 0.5f * (Z2.x - Zk.x);
            o.x = ((unsigned)f2bf(Li) << 16) | (unsigned)f2bf(Lr);
            o.y = ((unsigned)f2bf(Ri) << 16) | (unsigned)f2bf(Rr);
        }
        ro[bin] = o;
    }
}

// ---------------- Kernel 2: MFMA GEMM  C[frames, 80] = Amat x (Bhi + Blo) ----------
// Block: (b, mt of 32 frames, ksplit). 5 waves, wave = ctx group g (n-tile).
// A staged in LDS with XOR-swizzle (FULL 8KB: 2 x 16B per staging thread).
__global__ __launch_bounds__(320) void mlp_mfma_kernel(const unsigned short* __restrict__ Amat,
                                                       const unsigned int* __restrict__ Bwf,
                                                       float* __restrict__ PC) {
    __shared__ unsigned int Atile[2048];   // 32 rows x 128 k x bf16 = 8 KB
    int blk = blockIdx.x;                  // ((b*9 + mt)*KSPL + ksp)
    int ksp = blk % KSPL;
    int mt  = (blk / KSPL) % 9;
    int b   = blk / (KSPL * 9);
    int tid = threadIdx.x;
    int g   = tid >> 6;
    int l   = tid & 63;
    int lm  = l & 15;        // A row (frame-local) / C col-local
    int q   = l >> 4;

    size_t rowBase = (size_t)(b * FPADR + mt * 32);
    int k0 = ksp * 640;

    f32x4 acc0 = {0.f, 0.f, 0.f, 0.f};
    f32x4 acc1 = {0.f, 0.f, 0.f, 0.f};

    // staging thread map (tid<256): row = tid>>3, two 16B slots: bytes skq*16 and 128+skq*16
    int srow = tid >> 3;
    int skq  = tid & 7;
    const unsigned short* srcRow = Amat + (rowBase + srow) * KW + k0 + skq * 8;
    uint4 v0, v1;
    if (tid < 256) {
        v0 = *(const uint4*)(srcRow);
        v1 = *(const uint4*)(srcRow + 64);
    }

#pragma unroll
    for (int ch = 0; ch < CHPS; ch++) {
        __syncthreads();    // previous chunk's reads complete
        if (tid < 256) {
            int key = (srow & 7) << 4;
            int d0 = srow * 256 + ((skq * 16) ^ key);
            int d1 = srow * 256 + (((128 + skq * 16)) ^ key);   // bit7 untouched by key
            *(uint4*)((char*)Atile + d0) = v0;
            *(uint4*)((char*)Atile + d1) = v1;
        }
        __syncthreads();
        if (ch + 1 < CHPS && tid < 256) {
            const unsigned short* nsrc = srcRow + (ch + 1) * 128;
            v0 = *(const uint4*)(nsrc);
            v1 = *(const uint4*)(nsrc + 64);
        }

#pragma unroll
        for (int kk = 0; kk < 4; kk++) {
            int off0 = lm * 256 + ((kk * 64 + q * 16) ^ ((lm & 7) << 4));
            bf16x8 a0 = *(const bf16x8*)((const char*)Atile + off0);
            bf16x8 a1 = *(const bf16x8*)((const char*)Atile + off0 + 4096); // row+16, same XOR key
            int ks = ksp * 20 + ch * 4 + kk;
            const char* rec = (const char*)Bwf + ((size_t)ks * 10 + g) * 1024 + l * 16;
            bf16x8 bh = *(const bf16x8*)rec;
            bf16x8 bl = *(const bf16x8*)(rec + 5 * 1024);
            acc0 = __builtin_amdgcn_mfma_f32_16x16x32_bf16(a0, bh, acc0, 0, 0, 0);
            acc0 = __builtin_amdgcn_mfma_f32_16x16x32_bf16(a0, bl, acc0, 0, 0, 0);
            acc1 = __builtin_amdgcn_mfma_f32_16x16x32_bf16(a1, bh, acc1, 0, 0, 0);
            acc1 = __builtin_amdgcn_mfma_f32_16x16x32_bf16(a1, bl, acc1, 0, 0, 0);
        }
    }

    // C: col = g*16 + lm, row(frame-local) = q*4 + r (acc0), +16 (acc1)
    float* pc = PC + (((size_t)(ksp * 8 + b) * FPADR + mt * 32) * NCOL) + g * 16 + lm;
#pragma unroll
    for (int r = 0; r < 4; r++) {
        pc[(q * 4 + r) * NCOL] = acc0[r];
        pc[(16 + q * 4 + r) * NCOL] = acc1[r];
    }
}

// ---------------- Kernel 3: combine K-splits + context fold + MLP 2/3 -> mask -------
__global__ __launch_bounds__(256) void mask_kernel(const float* __restrict__ PC,
                                                   const float* __restrict__ b1,
                                                   const float* __restrict__ w2,
                                                   const float* __restrict__ b2,
                                                   const float* __restrict__ w3,
                                                   const float* __restrict__ b3,
                                                   float* __restrict__ mask) {
    int i = blockIdx.x * 256 + threadIdx.x;
    if (i >= BATCH * NFRM) return;
    int b = i / NFRM;
    int f = i - b * NFRM;

    float4 h0 = make_float4(0.f, 0.f, 0.f, 0.f), h1v = h0, h2v = h0, h3v = h0;
    for (int ksp = 0; ksp < KSPL; ksp++) {
#pragma unroll
        for (int g = 0; g < 5; g++) {
            int fr = f - 2 + g;
            if (fr < 0 || fr >= NFRM) continue;
            const float4* p = (const float4*)(PC + (((size_t)(ksp * 8 + b) * FPADR + fr) * NCOL) + g * 16);
            float4 a = p[0], bq = p[1], c = p[2], d = p[3];
            h0.x += a.x; h0.y += a.y; h0.z += a.z; h0.w += a.w;
            h1v.x += bq.x; h1v.y += bq.y; h1v.z += bq.z; h1v.w += bq.w;
            h2v.x += c.x; h2v.y += c.y; h2v.z += c.z; h2v.w += c.w;
            h3v.x += d.x; h3v.y += d.y; h3v.z += d.z; h3v.w += d.w;
        }
    }
    float h[16];
    *(float4*)&h[0]  = h0;  *(float4*)&h[4]  = h1v;
    *(float4*)&h[8]  = h2v; *(float4*)&h[12] = h3v;

#pragma unroll
    for (int j = 0; j < 15; j++) {
        float vv = h[j] + b1[j];
        h[j] = vv > 0.f ? vv : 0.f;
    }
    float hh[10];
#pragma unroll
    for (int k = 0; k < 10; k++) {
        float s = b2[k];
#pragma unroll
        for (int j = 0; j < 15; j++) s += h[j] * w2[j * 10 + k];
        hh[k] = s > 0.f ? s : 0.f;
    }
    float vv = b3[0];
#pragma unroll
    for (int k = 0; k < 10; k++) vv += hh[k] * w3[k];
    mask[i] = 1.f / (1.f + expf(-vv));
}

// ---------------- Kernel 4: analytic masked ISTFT (overlap-add ratio) ----------------
__global__ __launch_bounds__(256) void ola_kernel(const float* __restrict__ x,
                                                  const float* __restrict__ mask,
                                                  const float* __restrict__ wtab,
                                                  float* __restrict__ out) {
    int idx = blockIdx.x * 256 + threadIdx.x;
    int t  = idx & (TLEN - 1);
    int bc = idx >> 18;
    int b  = bc >> 1;
    int tau = t + PAD;
    int hi = tau >> 10; if (hi > NFRM - 1) hi = NFRM - 1;
    int lo = (tau - 3072) >> 10; if (lo < 0) lo = 0;
    float s0 = 0.f, s1 = 0.f;
    const float* mb = mask + b * NFRM;
    for (int f = lo; f <= hi; f++) {
        int n = tau - (f << 10);
        float w = wtab[n];
        float w2v = w * w;
        s0 += w2v;
        s1 += mb[f] * w2v;
    }
    float denom = (s0 > 1e-11f) ? s0 : 1.0f;
    out[idx] = x[idx] * (s1 / denom);
}

// ---------------- launch ----------------
extern "C" void kernel_launch(void* const* d_in, const int* in_sizes, int n_in,
                              void* d_out, int out_size, void* d_ws, size_t ws_size,
                              hipStream_t stream) {
    const float* x  = (const float*)d_in[0];
    const float* w1 = (const float*)d_in[1];
    const float* b1 = (const float*)d_in[2];
    const float* w2 = (const float*)d_in[3];
    const float* b2 = (const float*)d_in[4];
    const float* w3 = (const float*)d_in[5];
    const float* b3 = (const float*)d_in[6];

    char* wsp = (char*)d_ws;
    size_t off = 0;
    auto alloc = [&](size_t bytes) { void* p = wsp + off; off = (off + bytes + 511) & ~(size_t)511; return p; };

    unsigned short* Amat = (unsigned short*)alloc((size_t)BATCH * FPADR * KW * 2);     // 38.3 MB
    float* PC            = (float*)alloc((size_t)KSPL * 8 * FPADR * NCOL * 4);         // 9.6 MB
    unsigned int* Bwf    = (unsigned int*)alloc((size_t)NKS * 10 * 1024);              // 2.66 MB
    float* mask          = (float*)alloc((size_t)BATCH * NFRM * 4);
    float2* twg          = (float2*)alloc((size_t)2048 * 8);
    float* wtab          = (float*)alloc((size_t)N_FFT * 4);
    float* out = (float*)d_out;

    tables_kernel<<<16, 256, 0, stream>>>(twg, wtab);
    wprep_kernel<<<(NKS * 2 * 5 * 64 + 255) / 256, 256, 0, stream>>>(w1, Bwf);
    stft_kernel<<<BATCH * NFRM, 256, 0, stream>>>(x, twg, wtab, Amat);
    mlp_mfma_kernel<<<BATCH * 9 * KSPL, 320, 0, stream>>>(Amat, Bwf, PC);
    mask_kernel<<<(BATCH * NFRM + 255) / 256, 256, 0, stream>>>(PC, b1, w2, b2, w3, b3, mask);
    ola_kernel<<<(BATCH * 2 * TLEN) / 256, 256, 0, stream>>>(x, mask, wtab, out);
}

// Round 9
// 112.982 us; speedup vs baseline: 3.7052x; 1.2113x over previous
//
#include <hip/hip_runtime.h>
#include <math.h>

#define N_FFT 4096
#define HOP   1024
#define PAD   2048
#define NBINS 2049
#define NFRM  257
#define BATCH 8
#define TLEN  262144          // 2^18
#define TWO_PI 6.2831853071795864769f
#define INVSQRT2 0.70710678118654752440f

#define FPADR 288             // padded frames: 9 m-tiles of 32
#define BINPAD 2080           // padded bins (k-chunks of 128 => 65 chunks)
#define KW    (BINPAD * 4)    // 8320 k's (bin*4 + comp)
#define NKS   260             // k-steps of 32
#define KSPL  13              // K splits (each 5 chunks of 128 k)
#define CHPS  5               // chunks (of 128 k) per K-split
#define NCOL  80              // 5 ctx groups x 16 (j padded 15->16)

// padded LDS index (float2 units): breaks all 8^s stride bank conflicts
#define PIDX(i) ((i) + ((i) >> 4) + ((i) >> 8))

typedef short bf16x8 __attribute__((ext_vector_type(8)));
typedef float f32x4  __attribute__((ext_vector_type(4)));

__device__ __forceinline__ int reflect_idx(int s) {
    if (s < 0) s = -s;
    if (s >= TLEN) s = 2 * (TLEN - 1) - s;
    return s;
}

__device__ __forceinline__ unsigned short f2bf(float f) {
    unsigned int u = __float_as_uint(f);
    unsigned int r = (u + 0x7FFFu + ((u >> 16) & 1u)) >> 16;   // RTNE
    return (unsigned short)r;
}
__device__ __forceinline__ float bf2f(unsigned short h) {
    return __uint_as_float((unsigned int)h << 16);
}

__device__ __forceinline__ float2 cmul(float2 a, float2 b) {
    return make_float2(a.x * b.x - a.y * b.y, a.x * b.y + a.y * b.x);
}

// ---------------- Kernel T: trig/window tables ----------------
__global__ __launch_bounds__(256) void tables_kernel(float2* __restrict__ twg,
                                                     float* __restrict__ wtab) {
    int i = blockIdx.x * 256 + threadIdx.x;
    if (i < 2048) {
        float sv, cv;
        sincosf(-(TWO_PI * (float)i) / 4096.0f, &sv, &cv);
        twg[i] = make_float2(cv, sv);
    }
    if (i < N_FFT) {
        wtab[i] = 0.5f - 0.5f * cosf((TWO_PI / (float)N_FFT) * (float)i);
    }
}

// ---------------- Kernel W: pack w1 -> fragment-ready hi/lo bf16 ----------------
__global__ __launch_bounds__(256) void wprep_kernel(const float* __restrict__ w1,
                                                    unsigned int* __restrict__ Bwf) {
    int t = blockIdx.x * 256 + threadIdx.x;
    if (t >= NKS * 2 * 5 * 64) return;
    int l   = t & 63;
    int rec = t >> 6;
    int ks  = rec / 10;
    int r10 = rec - ks * 10;
    int hl  = r10 / 5;
    int g   = r10 - hl * 5;
    int q = l >> 4;
    int j = l & 15;

    unsigned short es[8];
#pragma unroll
    for (int e = 0; e < 8; e++) {
        int k   = ks * 32 + q * 8 + e;
        int bin = k >> 2;
        int cp  = k & 3;
        int refc = ((cp & 1) << 1) | (cp >> 1);   // {0,1,2,3}->{0,2,1,3}
        float w = 0.f;
        if (bin < NBINS && j < 15)
            w = w1[(size_t)(bin * 20 + g * 4 + refc) * 15 + j];
        unsigned short hi = f2bf(w);
        if (hl == 0) es[e] = hi;
        else         es[e] = f2bf(w - bf2f(hi));
    }
    uint4 o;
    o.x = (unsigned)es[0] | ((unsigned)es[1] << 16);
    o.y = (unsigned)es[2] | ((unsigned)es[3] << 16);
    o.z = (unsigned)es[4] | ((unsigned)es[5] << 16);
    o.w = (unsigned)es[6] | ((unsigned)es[7] << 16);
    *(uint4*)((char*)Bwf + (size_t)rec * 1024 + l * 16) = o;
}

// ---------------- Kernel 1: both channels in ONE 4096-pt complex FFT (radix-8) ------
// z = L + iR windowed; 4 radix-8 DIT stages with digit-reversed (base-8) input.
// Unpack L^ = 0.5(Z[k]+conj(Z[-k])), R^ = -0.5i(Z[k]-conj(Z[-k])); bf16 rows out.
__global__ __launch_bounds__(256) void stft_kernel(const float* __restrict__ x,
                                                   const float2* __restrict__ twg,
                                                   const float* __restrict__ wtab,
                                                   unsigned short* __restrict__ Amat) {
    __shared__ float2 zb[4368];     // 4096 + pads (34.9 KB)
    int wg = blockIdx.x;
    int f  = wg % NFRM;
    int b  = wg / NFRM;
    const float* xb = x + (size_t)b * 2 * TLEN;
    int tid = threadIdx.x;
    int base0 = f * HOP - PAD;

    for (int n = tid; n < 4096; n += 256) {
        int ri = reflect_idx(base0 + n);
        float wv = wtab[n];
        float lv = xb[ri] * wv;
        float rv = xb[TLEN + ri] * wv;
        int rev = ((n & 7) << 9) | (((n >> 3) & 7) << 6) | (((n >> 6) & 7) << 3) | ((n >> 9) & 7);
        zb[PIDX(rev)] = make_float2(lv, rv);
    }
    __syncthreads();

#pragma unroll
    for (int s = 0; s < 4; s++) {
        int E    = 1 << (3 * s);
        int step = 1 << (9 - 3 * s);
#pragma unroll
        for (int it = 0; it < 2; it++) {
            int t = tid + it * 256;           // 0..511
            int pos = t & (E - 1);
            int blk = t >> (3 * s);
            int base = (blk << (3 * s + 3)) + pos;

            float2 a0 = zb[PIDX(base)];
            float2 a1 = zb[PIDX(base + E)];
            float2 a2 = zb[PIDX(base + 2 * E)];
            float2 a3 = zb[PIDX(base + 3 * E)];
            float2 a4 = zb[PIDX(base + 4 * E)];
            float2 a5 = zb[PIDX(base + 5 * E)];
            float2 a6 = zb[PIDX(base + 6 * E)];
            float2 a7 = zb[PIDX(base + 7 * E)];

            if (s > 0) {
                float2 w1 = twg[pos * step];
                float2 w2 = cmul(w1, w1);
                float2 w3 = cmul(w2, w1);
                float2 w4 = cmul(w2, w2);
                float2 w5 = cmul(w3, w2);
                float2 w6 = cmul(w3, w3);
                float2 w7 = cmul(w4, w3);
                a1 = cmul(a1, w1); a2 = cmul(a2, w2); a3 = cmul(a3, w3);
                a4 = cmul(a4, w4); a5 = cmul(a5, w5); a6 = cmul(a6, w6);
                a7 = cmul(a7, w7);
            }

            // FFT-8 DIT (W8 = e^{-2pi i/8})
            float2 t0 = make_float2(a0.x + a4.x, a0.y + a4.y);
            float2 t1 = make_float2(a0.x - a4.x, a0.y - a4.y);
            float2 t2 = make_float2(a2.x + a6.x, a2.y + a6.y);
            float2 t3 = make_float2(a2.x - a6.x, a2.y - a6.y);
            float2 E0 = make_float2(t0.x + t2.x, t0.y + t2.y);
            float2 E2 = make_float2(t0.x - t2.x, t0.y - t2.y);
            float2 E1 = make_float2(t1.x + t3.y, t1.y - t3.x);   // t1 + (-j)t3
            float2 E3 = make_float2(t1.x - t3.y, t1.y + t3.x);
            float2 u0 = make_float2(a1.x + a5.x, a1.y + a5.y);
            float2 u1 = make_float2(a1.x - a5.x, a1.y - a5.y);
            float2 u2 = make_float2(a3.x + a7.x, a3.y + a7.y);
            float2 u3 = make_float2(a3.x - a7.x, a3.y - a7.y);
            float2 O0 = make_float2(u0.x + u2.x, u0.y + u2.y);
            float2 O2 = make_float2(u0.x - u2.x, u0.y - u2.y);
            float2 O1 = make_float2(u1.x + u3.y, u1.y - u3.x);
            float2 O3 = make_float2(u1.x - u3.y, u1.y + u3.x);
            float2 r1 = make_float2(INVSQRT2 * (O1.x + O1.y), INVSQRT2 * (O1.y - O1.x)); // *W8
            float2 r2 = make_float2(O2.y, -O2.x);                                        // *(-j)
            float2 r3 = make_float2(INVSQRT2 * (O3.y - O3.x), -INVSQRT2 * (O3.x + O3.y)); // *W8^3

            zb[PIDX(base)]         = make_float2(E0.x + O0.x, E0.y + O0.y);
            zb[PIDX(base + E)]     = make_float2(E1.x + r1.x, E1.y + r1.y);
            zb[PIDX(base + 2 * E)] = make_float2(E2.x + r2.x, E2.y + r2.y);
            zb[PIDX(base + 3 * E)] = make_float2(E3.x + r3.x, E3.y + r3.y);
            zb[PIDX(base + 4 * E)] = make_float2(E0.x - O0.x, E0.y - O0.y);
            zb[PIDX(base + 5 * E)] = make_float2(E1.x - r1.x, E1.y - r1.y);
            zb[PIDX(base + 6 * E)] = make_float2(E2.x - r2.x, E2.y - r2.y);
            zb[PIDX(base + 7 * E)] = make_float2(E3.x - r3.x, E3.y - r3.y);
        }
        __syncthreads();
    }

    uint2* ro = (uint2*)(Amat + ((size_t)b * FPADR + f) * KW);
    for (int bin = tid; bin < BINPAD; bin += 256) {
        uint2 o = make_uint2(0u, 0u);
        if (bin <= 2048) {
            float2 Zk = zb[PIDX(bin)];
            float2 Z2 = zb[PIDX((4096 - bin) & 4095)];
            float Lr = 0.5f * (Zk.x + Z2.x);
            float Li = 0.5f * (Zk.y - Z2.y);
            float Rr = 0.5f * (Zk.y + Z2.y);
            float Ri = 0.5f * (Z2.x - Zk.x);
            o.x = ((unsigned)f2bf(Li) << 16) | (unsigned)f2bf(Lr);
            o.y = ((unsigned)f2bf(Ri) << 16) | (unsigned)f2bf(Rr);
        }
        ro[bin] = o;
    }
}

// ---------------- Kernel 2: MFMA GEMM  C[frames, 80] = Amat x (Bhi + Blo) ----------
__global__ __launch_bounds__(320) void mlp_mfma_kernel(const unsigned short* __restrict__ Amat,
                                                       const unsigned int* __restrict__ Bwf,
                                                       float* __restrict__ PC) {
    __shared__ unsigned int Atile[2048];   // 32 rows x 128 k x bf16 = 8 KB
    int blk = blockIdx.x;                  // ((b*9 + mt)*KSPL + ksp)
    int ksp = blk % KSPL;
    int mt  = (blk / KSPL) % 9;
    int b   = blk / (KSPL * 9);
    int tid = threadIdx.x;
    int g   = tid >> 6;
    int l   = tid & 63;
    int lm  = l & 15;        // A row (frame-local) / C col-local
    int q   = l >> 4;

    size_t rowBase = (size_t)(b * FPADR + mt * 32);
    int k0 = ksp * 640;

    f32x4 acc0 = {0.f, 0.f, 0.f, 0.f};
    f32x4 acc1 = {0.f, 0.f, 0.f, 0.f};

    int srow = tid >> 3;
    int skq  = tid & 7;
    const unsigned short* srcRow = Amat + (rowBase + srow) * KW + k0 + skq * 8;
    uint4 v0, v1;
    if (tid < 256) {
        v0 = *(const uint4*)(srcRow);
        v1 = *(const uint4*)(srcRow + 64);
    }

#pragma unroll
    for (int ch = 0; ch < CHPS; ch++) {
        __syncthreads();    // previous chunk's reads complete
        if (tid < 256) {
            int key = (srow & 7) << 4;
            int d0 = srow * 256 + ((skq * 16) ^ key);
            int d1 = srow * 256 + (((128 + skq * 16)) ^ key);   // bit7 untouched by key
            *(uint4*)((char*)Atile + d0) = v0;
            *(uint4*)((char*)Atile + d1) = v1;
        }
        __syncthreads();
        if (ch + 1 < CHPS && tid < 256) {
            const unsigned short* nsrc = srcRow + (ch + 1) * 128;
            v0 = *(const uint4*)(nsrc);
            v1 = *(const uint4*)(nsrc + 64);
        }

#pragma unroll
        for (int kk = 0; kk < 4; kk++) {
            int off0 = lm * 256 + ((kk * 64 + q * 16) ^ ((lm & 7) << 4));
            bf16x8 a0 = *(const bf16x8*)((const char*)Atile + off0);
            bf16x8 a1 = *(const bf16x8*)((const char*)Atile + off0 + 4096); // row+16, same XOR key
            int ks = ksp * 20 + ch * 4 + kk;
            const char* rec = (const char*)Bwf + ((size_t)ks * 10 + g) * 1024 + l * 16;
            bf16x8 bh = *(const bf16x8*)rec;
            bf16x8 bl = *(const bf16x8*)(rec + 5 * 1024);
            acc0 = __builtin_amdgcn_mfma_f32_16x16x32_bf16(a0, bh, acc0, 0, 0, 0);
            acc0 = __builtin_amdgcn_mfma_f32_16x16x32_bf16(a0, bl, acc0, 0, 0, 0);
            acc1 = __builtin_amdgcn_mfma_f32_16x16x32_bf16(a1, bh, acc1, 0, 0, 0);
            acc1 = __builtin_amdgcn_mfma_f32_16x16x32_bf16(a1, bl, acc1, 0, 0, 0);
        }
    }

    float* pc = PC + (((size_t)(ksp * 8 + b) * FPADR + mt * 32) * NCOL) + g * 16 + lm;
#pragma unroll
    for (int r = 0; r < 4; r++) {
        pc[(q * 4 + r) * NCOL] = acc0[r];
        pc[(16 + q * 4 + r) * NCOL] = acc1[r];
    }
}

// ---------------- Kernel 3: combine K-splits + context fold + MLP 2/3 -> mask -------
__global__ __launch_bounds__(256) void mask_kernel(const float* __restrict__ PC,
                                                   const float* __restrict__ b1,
                                                   const float* __restrict__ w2,
                                                   const float* __restrict__ b2,
                                                   const float* __restrict__ w3,
                                                   const float* __restrict__ b3,
                                                   float* __restrict__ mask) {
    int i = blockIdx.x * 256 + threadIdx.x;
    if (i >= BATCH * NFRM) return;
    int b = i / NFRM;
    int f = i - b * NFRM;

    float4 h0 = make_float4(0.f, 0.f, 0.f, 0.f), h1v = h0, h2v = h0, h3v = h0;
    for (int ksp = 0; ksp < KSPL; ksp++) {
#pragma unroll
        for (int g = 0; g < 5; g++) {
            int fr = f - 2 + g;
            if (fr < 0 || fr >= NFRM) continue;
            const float4* p = (const float4*)(PC + (((size_t)(ksp * 8 + b) * FPADR + fr) * NCOL) + g * 16);
            float4 a = p[0], bq = p[1], c = p[2], d = p[3];
            h0.x += a.x; h0.y += a.y; h0.z += a.z; h0.w += a.w;
            h1v.x += bq.x; h1v.y += bq.y; h1v.z += bq.z; h1v.w += bq.w;
            h2v.x += c.x; h2v.y += c.y; h2v.z += c.z; h2v.w += c.w;
            h3v.x += d.x; h3v.y += d.y; h3v.z += d.z; h3v.w += d.w;
        }
    }
    float h[16];
    *(float4*)&h[0]  = h0;  *(float4*)&h[4]  = h1v;
    *(float4*)&h[8]  = h2v; *(float4*)&h[12] = h3v;

#pragma unroll
    for (int j = 0; j < 15; j++) {
        float vv = h[j] + b1[j];
        h[j] = vv > 0.f ? vv : 0.f;
    }
    float hh[10];
#pragma unroll
    for (int k = 0; k < 10; k++) {
        float s = b2[k];
#pragma unroll
        for (int j = 0; j < 15; j++) s += h[j] * w2[j * 10 + k];
        hh[k] = s > 0.f ? s : 0.f;
    }
    float vv = b3[0];
#pragma unroll
    for (int k = 0; k < 10; k++) vv += hh[k] * w3[k];
    mask[i] = 1.f / (1.f + expf(-vv));
}

// ---------------- Kernel 4: analytic masked ISTFT (overlap-add ratio) ----------------
__global__ __launch_bounds__(256) void ola_kernel(const float* __restrict__ x,
                                                  const float* __restrict__ mask,
                                                  const float* __restrict__ wtab,
                                                  float* __restrict__ out) {
    int idx = blockIdx.x * 256 + threadIdx.x;
    int t  = idx & (TLEN - 1);
    int bc = idx >> 18;
    int b  = bc >> 1;
    int tau = t + PAD;
    int hi = tau >> 10; if (hi > NFRM - 1) hi = NFRM - 1;
    int lo = (tau - 3072) >> 10; if (lo < 0) lo = 0;
    float s0 = 0.f, s1 = 0.f;
    const float* mb = mask + b * NFRM;
    for (int f = lo; f <= hi; f++) {
        int n = tau - (f << 10);
        float w = wtab[n];
        float w2v = w * w;
        s0 += w2v;
        s1 += mb[f] * w2v;
    }
    float denom = (s0 > 1e-11f) ? s0 : 1.0f;
    out[idx] = x[idx] * (s1 / denom);
}

// ---------------- launch ----------------
extern "C" void kernel_launch(void* const* d_in, const int* in_sizes, int n_in,
                              void* d_out, int out_size, void* d_ws, size_t ws_size,
                              hipStream_t stream) {
    const float* x  = (const float*)d_in[0];
    const float* w1 = (const float*)d_in[1];
    const float* b1 = (const float*)d_in[2];
    const float* w2 = (const float*)d_in[3];
    const float* b2 = (const float*)d_in[4];
    const float* w3 = (const float*)d_in[5];
    const float* b3 = (const float*)d_in[6];

    char* wsp = (char*)d_ws;
    size_t off = 0;
    auto alloc = [&](size_t bytes) { void* p = wsp + off; off = (off + bytes + 511) & ~(size_t)511; return p; };

    unsigned short* Amat = (unsigned short*)alloc((size_t)BATCH * FPADR * KW * 2);     // 38.3 MB
    float* PC            = (float*)alloc((size_t)KSPL * 8 * FPADR * NCOL * 4);         // 9.6 MB
    unsigned int* Bwf    = (unsigned int*)alloc((size_t)NKS * 10 * 1024);              // 2.66 MB
    float* mask          = (float*)alloc((size_t)BATCH * NFRM * 4);
    float2* twg          = (float2*)alloc((size_t)2048 * 8);
    float* wtab          = (float*)alloc((size_t)N_FFT * 4);
    float* out = (float*)d_out;

    tables_kernel<<<16, 256, 0, stream>>>(twg, wtab);
    wprep_kernel<<<(NKS * 2 * 5 * 64 + 255) / 256, 256, 0, stream>>>(w1, Bwf);
    stft_kernel<<<BATCH * NFRM, 256, 0, stream>>>(x, twg, wtab, Amat);
    mlp_mfma_kernel<<<BATCH * 9 * KSPL, 320, 0, stream>>>(Amat, Bwf, PC);
    mask_kernel<<<(BATCH * NFRM + 255) / 256, 256, 0, stream>>>(PC, b1, w2, b2, w3, b3, mask);
    ola_kernel<<<(BATCH * 2 * TLEN) / 256, 256, 0, stream>>>(x, mask, wtab, out);
}

// Round 10
// 88.623 us; speedup vs baseline: 4.7236x; 1.2749x over previous
//
#include <hip/hip_runtime.h>
#include <math.h>

#define N_FFT 4096
#define HOP   1024
#define PAD   2048
#define NBINS 2049
#define NFRM  257
#define BATCH 8
#define TLEN  262144          // 2^18
#define TWO_PI 6.2831853071795864769f
#define INVSQRT2 0.70710678118654752440f

#define FPADR 288             // padded frames: 9 m-tiles of 32
#define XPADL 299008          // padded xpad length: 288*1024 + 4096 (valid: 266240)
#define XVALID 266240         // TLEN + 2*PAD
#define KW    8192            // K = 2 ch x 4096 taps
#define NKS   256             // k-steps of 32
#define KSPL  8               // K splits (each 8 chunks of 128 k)
#define CHPS  8               // chunks per K-split
#define NCOL  80              // 5 ctx groups x 16 (j padded 15->16)

// padded LDS index (float2 units): breaks all 8^s stride bank conflicts
#define PIDX(i) ((i) + ((i) >> 4) + ((i) >> 8))

typedef short bf16x8 __attribute__((ext_vector_type(8)));
typedef float f32x4  __attribute__((ext_vector_type(4)));

__device__ __forceinline__ int reflect_idx(int s) {
    if (s < 0) s = -s;
    if (s >= TLEN) s = 2 * (TLEN - 1) - s;
    return s;
}

__device__ __forceinline__ unsigned short f2bf(float f) {
    unsigned int u = __float_as_uint(f);
    unsigned int r = (u + 0x7FFFu + ((u >> 16) & 1u)) >> 16;   // RTNE
    return (unsigned short)r;
}
__device__ __forceinline__ float bf2f(unsigned short h) {
    return __uint_as_float((unsigned int)h << 16);
}
__device__ __forceinline__ float2 cmul(float2 a, float2 b) {
    return make_float2(a.x * b.x - a.y * b.y, a.x * b.y + a.y * b.x);
}

// ---------------- Kernel T: trig/window tables ----------------
__global__ __launch_bounds__(256) void tables_kernel(float2* __restrict__ twg,
                                                     float* __restrict__ wtab) {
    int i = blockIdx.x * 256 + threadIdx.x;
    if (i < 2048) {
        float sv, cv;
        sincosf(-(TWO_PI * (float)i) / 4096.0f, &sv, &cv);
        twg[i] = make_float2(cv, sv);
    }
    if (i < N_FFT) {
        wtab[i] = 0.5f - 0.5f * cosf((TWO_PI / (float)N_FFT) * (float)i);
    }
}

// ---------------- Kernel X: materialize reflect-padded x as bf16 ----------------
__global__ __launch_bounds__(256) void xprep_kernel(const float* __restrict__ x,
                                                    unsigned short* __restrict__ xbf) {
    int bc = blockIdx.y;
    int i0 = (blockIdx.x * 256 + threadIdx.x) * 8;
    const float* sig = x + (size_t)bc * TLEN;
    unsigned short v[8];
#pragma unroll
    for (int e = 0; e < 8; e++) {
        int i = i0 + e;
        float val = 0.f;
        if (i < XVALID) val = sig[reflect_idx(i - PAD)];
        v[e] = f2bf(val);
    }
    uint4 o;
    o.x = (unsigned)v[0] | ((unsigned)v[1] << 16);
    o.y = (unsigned)v[2] | ((unsigned)v[3] << 16);
    o.z = (unsigned)v[4] | ((unsigned)v[5] << 16);
    o.w = (unsigned)v[6] | ((unsigned)v[7] << 16);
    *(uint4*)(xbf + (size_t)bc * XPADL + i0) = o;
}

// ---------------- Kernel D: FIR kernels from w1 rows via 4096-pt FFT (radix-8) ------
// c[n] = Re{ sum_bin (a - i b) e^{-2pi i n bin/4096} }, a=w1[..re..], b=w1[..im..];
// then D[n] = win[n] * c[n].  One block per (j,g,ch): 150 blocks.
__global__ __launch_bounds__(256) void dfft_kernel(const float* __restrict__ w1,
                                                   const float2* __restrict__ twg,
                                                   const float* __restrict__ wtab,
                                                   float* __restrict__ cD) {
    __shared__ float2 zb[4368];     // 4096 + pads (34.9 KB)
    int bid = blockIdx.x;           // (j*5+g)*2 + ch
    int ch  = bid & 1;
    int jg  = bid >> 1;
    int g   = jg % 5;
    int j   = jg / 5;
    int cA  = ch;                   // re coeff: Lr=0 / Rr=1
    int cB  = ch + 2;               // im coeff: Li=2 / Ri=3
    int tid = threadIdx.x;

    for (int bin = tid; bin < 4096; bin += 256) {
        float ar = 0.f, ai = 0.f;
        if (bin <= 2048) {
            ar =  w1[(size_t)(bin * 20 + g * 4 + cA) * 15 + j];
            ai = -w1[(size_t)(bin * 20 + g * 4 + cB) * 15 + j];
        }
        int rev = ((bin & 7) << 9) | (((bin >> 3) & 7) << 6) | (((bin >> 6) & 7) << 3) | ((bin >> 9) & 7);
        zb[PIDX(rev)] = make_float2(ar, ai);
    }
    __syncthreads();

#pragma unroll
    for (int s = 0; s < 4; s++) {
        int E    = 1 << (3 * s);
        int step = 1 << (9 - 3 * s);
#pragma unroll
        for (int it = 0; it < 2; it++) {
            int t = tid + it * 256;           // 0..511
            int pos = t & (E - 1);
            int blk = t >> (3 * s);
            int base = (blk << (3 * s + 3)) + pos;

            float2 a0 = zb[PIDX(base)];
            float2 a1 = zb[PIDX(base + E)];
            float2 a2 = zb[PIDX(base + 2 * E)];
            float2 a3 = zb[PIDX(base + 3 * E)];
            float2 a4 = zb[PIDX(base + 4 * E)];
            float2 a5 = zb[PIDX(base + 5 * E)];
            float2 a6 = zb[PIDX(base + 6 * E)];
            float2 a7 = zb[PIDX(base + 7 * E)];

            if (s > 0) {
                float2 w1t = twg[pos * step];
                float2 w2 = cmul(w1t, w1t);
                float2 w3 = cmul(w2, w1t);
                float2 w4 = cmul(w2, w2);
                float2 w5 = cmul(w3, w2);
                float2 w6 = cmul(w3, w3);
                float2 w7 = cmul(w4, w3);
                a1 = cmul(a1, w1t); a2 = cmul(a2, w2); a3 = cmul(a3, w3);
                a4 = cmul(a4, w4);  a5 = cmul(a5, w5); a6 = cmul(a6, w6);
                a7 = cmul(a7, w7);
            }

            float2 t0 = make_float2(a0.x + a4.x, a0.y + a4.y);
            float2 t1 = make_float2(a0.x - a4.x, a0.y - a4.y);
            float2 t2 = make_float2(a2.x + a6.x, a2.y + a6.y);
            float2 t3 = make_float2(a2.x - a6.x, a2.y - a6.y);
            float2 E0 = make_float2(t0.x + t2.x, t0.y + t2.y);
            float2 E2 = make_float2(t0.x - t2.x, t0.y - t2.y);
            float2 E1 = make_float2(t1.x + t3.y, t1.y - t3.x);
            float2 E3 = make_float2(t1.x - t3.y, t1.y + t3.x);
            float2 u0 = make_float2(a1.x + a5.x, a1.y + a5.y);
            float2 u1 = make_float2(a1.x - a5.x, a1.y - a5.y);
            float2 u2 = make_float2(a3.x + a7.x, a3.y + a7.y);
            float2 u3 = make_float2(a3.x - a7.x, a3.y - a7.y);
            float2 O0 = make_float2(u0.x + u2.x, u0.y + u2.y);
            float2 O2 = make_float2(u0.x - u2.x, u0.y - u2.y);
            float2 O1 = make_float2(u1.x + u3.y, u1.y - u3.x);
            float2 O3 = make_float2(u1.x - u3.y, u1.y + u3.x);
            float2 r1 = make_float2(INVSQRT2 * (O1.x + O1.y), INVSQRT2 * (O1.y - O1.x));
            float2 r2 = make_float2(O2.y, -O2.x);
            float2 r3 = make_float2(INVSQRT2 * (O3.y - O3.x), -INVSQRT2 * (O3.x + O3.y));

            zb[PIDX(base)]         = make_float2(E0.x + O0.x, E0.y + O0.y);
            zb[PIDX(base + E)]     = make_float2(E1.x + r1.x, E1.y + r1.y);
            zb[PIDX(base + 2 * E)] = make_float2(E2.x + r2.x, E2.y + r2.y);
            zb[PIDX(base + 3 * E)] = make_float2(E3.x + r3.x, E3.y + r3.y);
            zb[PIDX(base + 4 * E)] = make_float2(E0.x - O0.x, E0.y - O0.y);
            zb[PIDX(base + 5 * E)] = make_float2(E1.x - r1.x, E1.y - r1.y);
            zb[PIDX(base + 6 * E)] = make_float2(E2.x - r2.x, E2.y - r2.y);
            zb[PIDX(base + 7 * E)] = make_float2(E3.x - r3.x, E3.y - r3.y);
        }
        __syncthreads();
    }

    float* outc = cD + (size_t)bid * 4096;
    for (int n = tid; n < 4096; n += 256)
        outc[n] = wtab[n] * zb[PIDX(n)].x;
}

// ---------------- Kernel P: pack D -> fragment-ready hi/lo bf16 ----------------
// Record (ks, hl, g): 1KB = 64 lanes x 16B. Lane l: col j = l&15, elems e at
// k = ks*32 + (l>>4)*8 + e; ch = k>>12, n = k&4095.
__global__ __launch_bounds__(256) void dprep_kernel(const float* __restrict__ cD,
                                                    unsigned int* __restrict__ Bwf) {
    int t = blockIdx.x * 256 + threadIdx.x;
    if (t >= NKS * 2 * 5 * 64) return;
    int l   = t & 63;
    int rec = t >> 6;
    int ks  = rec / 10;
    int r10 = rec - ks * 10;
    int hl  = r10 / 5;
    int g   = r10 - hl * 5;
    int q = l >> 4;
    int j = l & 15;

    unsigned short es[8];
#pragma unroll
    for (int e = 0; e < 8; e++) {
        int k  = ks * 32 + q * 8 + e;
        int ch = k >> 12;
        int n  = k & 4095;
        float w = 0.f;
        if (j < 15)
            w = cD[((size_t)(j * 5 + g) * 2 + ch) * 4096 + n];
        unsigned short hi = f2bf(w);
        if (hl == 0) es[e] = hi;
        else         es[e] = f2bf(w - bf2f(hi));
    }
    uint4 o;
    o.x = (unsigned)es[0] | ((unsigned)es[1] << 16);
    o.y = (unsigned)es[2] | ((unsigned)es[3] << 16);
    o.z = (unsigned)es[4] | ((unsigned)es[5] << 16);
    o.w = (unsigned)es[6] | ((unsigned)es[7] << 16);
    *(uint4*)((char*)Bwf + (size_t)rec * 1024 + l * 16) = o;
}

// ---------------- Kernel 2: MFMA GEMM  PC[(ksp,b), fr, (g,j)] = xbf x (Dhi + Dlo) ---
// Block: (b, mt of 32 frames, ksp). 5 waves, wave = ctx group g (n-tile).
// A rows are raw padded-signal windows: A[fr, k] = xbf[b,ch, fr*1024 + n].
__global__ __launch_bounds__(320) void mlp_mfma_kernel(const unsigned short* __restrict__ xbf,
                                                       const unsigned int* __restrict__ Bwf,
                                                       float* __restrict__ PC) {
    __shared__ unsigned int Atile[2048];   // 32 rows x 128 k x bf16 = 8 KB
    int blk = blockIdx.x;                  // ((b*9 + mt)*KSPL + ksp)
    int ksp = blk & 7;
    int mt  = (blk >> 3) % 9;
    int b   = blk / 72;
    int tid = threadIdx.x;
    int g   = tid >> 6;
    int l   = tid & 63;
    int lm  = l & 15;        // A row (frame-local) / C col-local
    int q   = l >> 4;

    int ch = ksp >> 2;
    int n0 = (ksp & 3) * 1024;

    f32x4 acc0 = {0.f, 0.f, 0.f, 0.f};
    f32x4 acc1 = {0.f, 0.f, 0.f, 0.f};

    int srow = tid >> 3;
    int skq  = tid & 7;
    const unsigned short* srcRow = xbf + (size_t)(b * 2 + ch) * XPADL
                                 + (size_t)(mt * 32 + srow) * 1024 + n0 + skq * 8;
    uint4 v0, v1;
    if (tid < 256) {
        v0 = *(const uint4*)(srcRow);
        v1 = *(const uint4*)(srcRow + 64);
    }

#pragma unroll
    for (int cc = 0; cc < CHPS; cc++) {
        __syncthreads();    // previous chunk's reads complete
        if (tid < 256) {
            int key = (srow & 7) << 4;
            int d0 = srow * 256 + ((skq * 16) ^ key);
            int d1 = srow * 256 + (((128 + skq * 16)) ^ key);   // bit7 untouched by key
            *(uint4*)((char*)Atile + d0) = v0;
            *(uint4*)((char*)Atile + d1) = v1;
        }
        __syncthreads();
        if (cc + 1 < CHPS && tid < 256) {
            const unsigned short* nsrc = srcRow + (cc + 1) * 128;
            v0 = *(const uint4*)(nsrc);
            v1 = *(const uint4*)(nsrc + 64);
        }

#pragma unroll
        for (int kk = 0; kk < 4; kk++) {
            int off0 = lm * 256 + ((kk * 64 + q * 16) ^ ((lm & 7) << 4));
            bf16x8 a0 = *(const bf16x8*)((const char*)Atile + off0);
            bf16x8 a1 = *(const bf16x8*)((const char*)Atile + off0 + 4096); // row+16
            int ks = ksp * 32 + cc * 4 + kk;
            const char* rec = (const char*)Bwf + ((size_t)ks * 10 + g) * 1024 + l * 16;
            bf16x8 bh = *(const bf16x8*)rec;
            bf16x8 bl = *(const bf16x8*)(rec + 5 * 1024);
            acc0 = __builtin_amdgcn_mfma_f32_16x16x32_bf16(a0, bh, acc0, 0, 0, 0);
            acc0 = __builtin_amdgcn_mfma_f32_16x16x32_bf16(a0, bl, acc0, 0, 0, 0);
            acc1 = __builtin_amdgcn_mfma_f32_16x16x32_bf16(a1, bh, acc1, 0, 0, 0);
            acc1 = __builtin_amdgcn_mfma_f32_16x16x32_bf16(a1, bl, acc1, 0, 0, 0);
        }
    }

    float* pc = PC + (((size_t)(ksp * 8 + b) * FPADR + mt * 32) * NCOL) + g * 16 + lm;
#pragma unroll
    for (int r = 0; r < 4; r++) {
        pc[(q * 4 + r) * NCOL] = acc0[r];
        pc[(16 + q * 4 + r) * NCOL] = acc1[r];
    }
}

// ---------------- Kernel 3: combine K-splits + context fold + MLP 2/3 -> mask -------
__global__ __launch_bounds__(256) void mask_kernel(const float* __restrict__ PC,
                                                   const float* __restrict__ b1,
                                                   const float* __restrict__ w2,
                                                   const float* __restrict__ b2,
                                                   const float* __restrict__ w3,
                                                   const float* __restrict__ b3,
                                                   float* __restrict__ mask) {
    int i = blockIdx.x * 256 + threadIdx.x;
    if (i >= BATCH * NFRM) return;
    int b = i / NFRM;
    int f = i - b * NFRM;

    float4 h0 = make_float4(0.f, 0.f, 0.f, 0.f), h1v = h0, h2v = h0, h3v = h0;
    for (int ksp = 0; ksp < KSPL; ksp++) {
#pragma unroll
        for (int g = 0; g < 5; g++) {
            int fr = f - 2 + g;
            if (fr < 0 || fr >= NFRM) continue;
            const float4* p = (const float4*)(PC + (((size_t)(ksp * 8 + b) * FPADR + fr) * NCOL) + g * 16);
            float4 a = p[0], bq = p[1], c = p[2], d = p[3];
            h0.x += a.x; h0.y += a.y; h0.z += a.z; h0.w += a.w;
            h1v.x += bq.x; h1v.y += bq.y; h1v.z += bq.z; h1v.w += bq.w;
            h2v.x += c.x; h2v.y += c.y; h2v.z += c.z; h2v.w += c.w;
            h3v.x += d.x; h3v.y += d.y; h3v.z += d.z; h3v.w += d.w;
        }
    }
    float h[16];
    *(float4*)&h[0]  = h0;  *(float4*)&h[4]  = h1v;
    *(float4*)&h[8]  = h2v; *(float4*)&h[12] = h3v;

#pragma unroll
    for (int j = 0; j < 15; j++) {
        float vv = h[j] + b1[j];
        h[j] = vv > 0.f ? vv : 0.f;
    }
    float hh[10];
#pragma unroll
    for (int k = 0; k < 10; k++) {
        float s = b2[k];
#pragma unroll
        for (int j = 0; j < 15; j++) s += h[j] * w2[j * 10 + k];
        hh[k] = s > 0.f ? s : 0.f;
    }
    float vv = b3[0];
#pragma unroll
    for (int k = 0; k < 10; k++) vv += hh[k] * w3[k];
    mask[i] = 1.f / (1.f + expf(-vv));
}

// ---------------- Kernel 4: analytic masked ISTFT (overlap-add ratio) ----------------
__global__ __launch_bounds__(256) void ola_kernel(const float* __restrict__ x,
                                                  const float* __restrict__ mask,
                                                  const float* __restrict__ wtab,
                                                  float* __restrict__ out) {
    int idx = blockIdx.x * 256 + threadIdx.x;
    int t  = idx & (TLEN - 1);
    int bc = idx >> 18;
    int b  = bc >> 1;
    int tau = t + PAD;
    int hi = tau >> 10; if (hi > NFRM - 1) hi = NFRM - 1;
    int lo = (tau - 3072) >> 10; if (lo < 0) lo = 0;
    float s0 = 0.f, s1 = 0.f;
    const float* mb = mask + b * NFRM;
    for (int f = lo; f <= hi; f++) {
        int n = tau - (f << 10);
        float w = wtab[n];
        float w2v = w * w;
        s0 += w2v;
        s1 += mb[f] * w2v;
    }
    float denom = (s0 > 1e-11f) ? s0 : 1.0f;
    out[idx] = x[idx] * (s1 / denom);
}

// ---------------- launch ----------------
extern "C" void kernel_launch(void* const* d_in, const int* in_sizes, int n_in,
                              void* d_out, int out_size, void* d_ws, size_t ws_size,
                              hipStream_t stream) {
    const float* x  = (const float*)d_in[0];
    const float* w1 = (const float*)d_in[1];
    const float* b1 = (const float*)d_in[2];
    const float* w2 = (const float*)d_in[3];
    const float* b2 = (const float*)d_in[4];
    const float* w3 = (const float*)d_in[5];
    const float* b3 = (const float*)d_in[6];

    char* wsp = (char*)d_ws;
    size_t off = 0;
    auto alloc = [&](size_t bytes) { void* p = wsp + off; off = (off + bytes + 511) & ~(size_t)511; return p; };

    unsigned short* xbf = (unsigned short*)alloc((size_t)16 * XPADL * 2);            // 9.57 MB
    float* cD           = (float*)alloc((size_t)150 * 4096 * 4);                     // 2.46 MB
    unsigned int* Bwf   = (unsigned int*)alloc((size_t)NKS * 10 * 1024);             // 2.62 MB
    float* PC           = (float*)alloc((size_t)KSPL * 8 * FPADR * NCOL * 4);        // 5.90 MB
    float* mask         = (float*)alloc((size_t)BATCH * NFRM * 4);
    float2* twg         = (float2*)alloc((size_t)2048 * 8);
    float* wtab         = (float*)alloc((size_t)N_FFT * 4);
    float* out = (float*)d_out;

    tables_kernel<<<16, 256, 0, stream>>>(twg, wtab);
    xprep_kernel<<<dim3(XPADL / (256 * 8), 16), 256, 0, stream>>>(x, xbf);
    dfft_kernel<<<150, 256, 0, stream>>>(w1, twg, wtab, cD);
    dprep_kernel<<<(NKS * 2 * 5 * 64 + 255) / 256, 256, 0, stream>>>(cD, Bwf);
    mlp_mfma_kernel<<<BATCH * 9 * KSPL, 320, 0, stream>>>(xbf, Bwf, PC);
    mask_kernel<<<(BATCH * NFRM + 255) / 256, 256, 0, stream>>>(PC, b1, w2, b2, w3, b3, mask);
    ola_kernel<<<(BATCH * 2 * TLEN) / 256, 256, 0, stream>>>(x, mask, wtab, out);
}